// Round 1
// baseline (376.156 us; speedup 1.0000x reference)
//
#include <hip/hip_runtime.h>
#include <hip/hip_bf16.h>

// LoRA-GCN: out = propagate(x @ W_B^T @ W_A^T) + bias
// Key algebraic fusion: propagate is row-linear, so we propagate the rank-3
// intermediate z = x @ W_B^T (N x 3) and apply W_A^T afterwards.

#define RANK 3
#define IN_DIM 256
#define OUT_DIM 64

// ---------------------------------------------------------------------------
// Detect whether edge_index arrived as int64 (high words all zero) or int32.
// flag = 1 -> int64 (stride 2 in int32 units), flag = 0 -> int32.
__global__ void detect_kernel(const int* __restrict__ idx, int nsample, int* flag) {
    __shared__ int s_nz;
    if (threadIdx.x == 0) s_nz = 0;
    __syncthreads();
    int nz = 0;
    for (int i = threadIdx.x; i < nsample; i += blockDim.x)
        nz |= idx[2 * i + 1];           // high word under int64 hypothesis
    if (nz) s_nz = 1;                   // race-benign flag set
    __syncthreads();
    if (threadIdx.x == 0) *flag = (s_nz == 0) ? 1 : 0;
}

// ---------------------------------------------------------------------------
// z = x @ W_B^T : one 64-lane wave per node; lane loads float4 of x row.
__global__ void zproj_kernel(const float* __restrict__ x,
                             const float* __restrict__ WB,   // [3][256]
                             float* __restrict__ z, int N) {
    int gtid = blockIdx.x * blockDim.x + threadIdx.x;
    int node = gtid >> 6;
    int lane = threadIdx.x & 63;
    if (node >= N) return;

    const float4* x4 = reinterpret_cast<const float4*>(x + (size_t)node * IN_DIM);
    float4 xv = x4[lane];
    float4 w0 = reinterpret_cast<const float4*>(WB)[lane];
    float4 w1 = reinterpret_cast<const float4*>(WB + IN_DIM)[lane];
    float4 w2 = reinterpret_cast<const float4*>(WB + 2 * IN_DIM)[lane];

    float p0 = xv.x * w0.x + xv.y * w0.y + xv.z * w0.z + xv.w * w0.w;
    float p1 = xv.x * w1.x + xv.y * w1.y + xv.z * w1.z + xv.w * w1.w;
    float p2 = xv.x * w2.x + xv.y * w2.y + xv.z * w2.z + xv.w * w2.w;

    #pragma unroll
    for (int m = 32; m > 0; m >>= 1) {
        p0 += __shfl_xor(p0, m);
        p1 += __shfl_xor(p1, m);
        p2 += __shfl_xor(p2, m);
    }
    if (lane == 0) {
        z[(size_t)node * RANK + 0] = p0;
        z[(size_t)node * RANK + 1] = p1;
        z[(size_t)node * RANK + 2] = p2;
    }
}

// ---------------------------------------------------------------------------
// degree: deg[col] += 1 for each non-self-loop edge.
__global__ void deg_kernel(const int* __restrict__ idx, int E,
                           const int* __restrict__ flag,
                           float* __restrict__ deg) {
    int stride = (*flag) ? 2 : 1;
    const int* rowp = idx;
    const int* colp = idx + (size_t)E * stride;
    int step = gridDim.x * blockDim.x;
    for (int e = blockIdx.x * blockDim.x + threadIdx.x; e < E; e += step) {
        int r = rowp[(size_t)e * stride];
        int c = colp[(size_t)e * stride];
        if (r != c) atomicAdd(&deg[c], 1.0f);
    }
}

// ---------------------------------------------------------------------------
// dinv = rsqrt(deg+1); agg = (1/deg_total) * z   (self-loop contribution)
__global__ void dinv_self_kernel(const float* __restrict__ z,
                                 const float* __restrict__ deg,
                                 float* __restrict__ dinv,
                                 float* __restrict__ agg, int N) {
    int n = blockIdx.x * blockDim.x + threadIdx.x;
    if (n >= N) return;
    float d = deg[n] + 1.0f;
    float di = rsqrtf(d);
    dinv[n] = di;
    float w = 1.0f / d;
    agg[(size_t)n * RANK + 0] = w * z[(size_t)n * RANK + 0];
    agg[(size_t)n * RANK + 1] = w * z[(size_t)n * RANK + 1];
    agg[(size_t)n * RANK + 2] = w * z[(size_t)n * RANK + 2];
}

// ---------------------------------------------------------------------------
// scatter: agg[col] += dinv[row]*dinv[col] * z[row]  (rank-3 payload)
__global__ void scatter_kernel(const int* __restrict__ idx, int E,
                               const int* __restrict__ flag,
                               const float* __restrict__ z,
                               const float* __restrict__ dinv,
                               float* __restrict__ agg) {
    int stride = (*flag) ? 2 : 1;
    const int* rowp = idx;
    const int* colp = idx + (size_t)E * stride;
    int step = gridDim.x * blockDim.x;
    for (int e = blockIdx.x * blockDim.x + threadIdx.x; e < E; e += step) {
        int r = rowp[(size_t)e * stride];
        int c = colp[(size_t)e * stride];
        if (r != c) {
            float w = dinv[r] * dinv[c];
            atomicAdd(&agg[(size_t)c * RANK + 0], w * z[(size_t)r * RANK + 0]);
            atomicAdd(&agg[(size_t)c * RANK + 1], w * z[(size_t)r * RANK + 1]);
            atomicAdd(&agg[(size_t)c * RANK + 2], w * z[(size_t)r * RANK + 2]);
        }
    }
}

// ---------------------------------------------------------------------------
// out[n][j] = sum_k agg[n][k] * W_A[j][k] + bias[j]; 64 threads per node.
__global__ void out_kernel(const float* __restrict__ agg,
                           const float* __restrict__ WA,   // [64][3]
                           const float* __restrict__ bias,
                           float* __restrict__ out, int N) {
    int t = blockIdx.x * blockDim.x + threadIdx.x;
    int n = t >> 6;
    int j = t & 63;
    if (n >= N) return;
    float a0 = agg[(size_t)n * RANK + 0];
    float a1 = agg[(size_t)n * RANK + 1];
    float a2 = agg[(size_t)n * RANK + 2];
    out[(size_t)n * OUT_DIM + j] =
        a0 * WA[j * RANK + 0] + a1 * WA[j * RANK + 1] + a2 * WA[j * RANK + 2] + bias[j];
}

extern "C" void kernel_launch(void* const* d_in, const int* in_sizes, int n_in,
                              void* d_out, int out_size, void* d_ws, size_t ws_size,
                              hipStream_t stream) {
    const float* x    = (const float*)d_in[0];
    const int*   idx  = (const int*)d_in[1];
    const float* WB   = (const float*)d_in[2];
    const float* WA   = (const float*)d_in[3];
    const float* bias = (const float*)d_in[4];
    float* out = (float*)d_out;

    const int N = in_sizes[0] / IN_DIM;     // 100000
    const int E = in_sizes[1] / 2;          // 1600000

    // workspace carve-out (256B aligned)
    auto align256 = [](size_t o) { return (o + 255) & ~(size_t)255; };
    char* ws = (char*)d_ws;
    size_t off = 0;
    int*   flag = (int*)(ws + off);      off = align256(off + sizeof(int));
    float* z    = (float*)(ws + off);    off = align256(off + (size_t)N * RANK * sizeof(float));
    float* deg  = (float*)(ws + off);    off = align256(off + (size_t)N * sizeof(float));
    float* dinv = (float*)(ws + off);    off = align256(off + (size_t)N * sizeof(float));
    float* agg  = (float*)(ws + off);    off = align256(off + (size_t)N * RANK * sizeof(float));
    (void)ws_size;

    // deg must start at zero every call
    hipMemsetAsync(deg, 0, (size_t)N * sizeof(float), stream);

    int nsample = E < 1024 ? E : 1024;
    detect_kernel<<<1, 256, 0, stream>>>(idx, nsample, flag);

    // z = x @ W_B^T   (one wave per node)
    {
        int blocks = (N + 3) / 4;               // 4 waves (nodes) per 256-thread block
        zproj_kernel<<<blocks, 256, 0, stream>>>(x, WB, z, N);
    }

    // degree accumulation
    deg_kernel<<<2048, 256, 0, stream>>>(idx, E, flag, deg);

    // dinv + self-loop init of agg
    dinv_self_kernel<<<(N + 255) / 256, 256, 0, stream>>>(z, deg, dinv, agg, N);

    // edge scatter (rank-3 payload)
    scatter_kernel<<<2048, 256, 0, stream>>>(idx, E, flag, z, dinv, agg);

    // epilogue: out = agg @ W_A^T + bias
    {
        long long total = (long long)N * OUT_DIM;
        int blocks = (int)((total + 255) / 256);
        out_kernel<<<blocks, 256, 0, stream>>>(agg, WA, bias, out, N);
    }
}